// Round 5
// baseline (621.273 us; speedup 1.0000x reference)
//
#include <hip/hip_runtime.h>
#include <math.h>

#define C_DIM 512
#define T_DIM 2048
#define B_DIM 8

typedef _Float16 f16;
typedef __attribute__((ext_vector_type(8))) _Float16 half8;
typedef __attribute__((ext_vector_type(4))) _Float16 half4;
typedef __attribute__((ext_vector_type(4))) float floatx4;

// ---------------------------------------------------------------------------
// fp32 [512][512] weights -> fp16. z=0/1 fill merged theta|phi [1024][512].
// ---------------------------------------------------------------------------
__global__ __launch_bounds__(256) void convert_w_kernel(
    const float* __restrict__ w0, const float* __restrict__ w1,
    const float* __restrict__ w2, const float* __restrict__ w3,
    f16* __restrict__ o0, f16* __restrict__ o1,
    f16* __restrict__ o2, f16* __restrict__ o3)
{
    const float* src; f16* dst;
    switch (blockIdx.z) {
        case 0:  src = w0; dst = o0; break;
        case 1:  src = w1; dst = o1; break;
        case 2:  src = w2; dst = o2; break;
        default: src = w3; dst = o3; break;
    }
    const int idx = (blockIdx.x * 256 + threadIdx.x) * 4;
    const float4 v = *(const float4*)(src + idx);
    half4 h; h[0] = (f16)v.x; h[1] = (f16)v.y; h[2] = (f16)v.z; h[3] = (f16)v.w;
    *(half4*)(dst + idx) = h;
}

__global__ __launch_bounds__(256) void concat_bias_kernel(
    const float* __restrict__ b0, const float* __restrict__ b1,
    float* __restrict__ o)
{
    const int i = blockIdx.x * 256 + threadIdx.x;   // 1024 threads
    o[i] = (i < 512) ? b0[i] : b1[i - 512];
}

// ---------------------------------------------------------------------------
// x [B][C][T] fp32 -> xt [B][T][C] fp16 (32x32 LDS tile transpose)
// ---------------------------------------------------------------------------
__global__ __launch_bounds__(256) void transpose_x_kernel(
    const float* __restrict__ x, f16* __restrict__ xt)
{
    __shared__ float xs[32][33];
    const int b  = blockIdx.z;
    const int t0 = blockIdx.x * 32, c0 = blockIdx.y * 32;
    const float* xb = x + (size_t)b * C_DIM * T_DIM;
    const int r = threadIdx.x >> 3, q = threadIdx.x & 7;

    const float4 v = *(const float4*)(xb + (size_t)(c0 + r) * T_DIM + t0 + q * 4);
    xs[r][q * 4 + 0] = v.x; xs[r][q * 4 + 1] = v.y;
    xs[r][q * 4 + 2] = v.z; xs[r][q * 4 + 3] = v.w;
    __syncthreads();

    f16* xtb = xt + (size_t)b * C_DIM * T_DIM;
    half4 h;
    h[0] = (f16)xs[q * 4 + 0][r]; h[1] = (f16)xs[q * 4 + 1][r];
    h[2] = (f16)xs[q * 4 + 2][r]; h[3] = (f16)xs[q * 4 + 3][r];
    *(half4*)(xtb + (size_t)(t0 + r) * C_DIM + c0 + q * 4) = h;
}

// ---------------------------------------------------------------------------
// TN MFMA GEMM: C[i][j] = sum_k A[i][k] * B[j][k]
// 128x128 tile, BK=32. Register-staged prefetch at DISTANCE 2: global_load
// for tile t+2 issued at iter t. Plain VGPR loads are not drained at
// s_barrier (unlike global_load_lds), so each load gets ~2 iterations of
// flight. LDS double-buffered, ONE barrier per iter (ordering:
// read(t-2) < barrier(t-1) < write(t) < barrier(t) < read(t)).
// XOR slot swizzle (slot = ch ^ (row&3)) on write and frag-read.
// MODE: 0 = f16 store; 1 = f16 relu(+bias[col]); 2 = f16 relu(+bias[row]);
// 3 = fp32 relu(+bias[row]) + resid.
// ---------------------------------------------------------------------------
template<int MODE>
__global__ __launch_bounds__(256) void gemm_tn(
    const f16* __restrict__ A, size_t sA, int lda,
    const f16* __restrict__ B, size_t sB, int ldb,
    void* __restrict__ Cp, size_t sC, int ldc,
    const float* __restrict__ bias,
    const float* __restrict__ resid, size_t sR,
    int K)
{
    __shared__ __align__(16) f16 As[2][128 * 32];   // 2 x 8 KB, unpadded
    __shared__ __align__(16) f16 Bs[2][128 * 32];

    // 4x4-supertile block swizzle: 16 consecutive blocks share 4 A + 4 B tiles
    const int gx = gridDim.x;
    const int flat = blockIdx.y * gx + blockIdx.x;
    const int jsc = gx >> 2;                  // j-supertiles per row
    const int sh = (jsc <= 1) ? 0 : (31 - __builtin_clz(jsc));
    const int s = flat >> 4, rem = flat & 15;
    const int i0 = ((s >> sh) * 4 + (rem >> 2)) * 128;
    const int j0 = (((jsc <= 1) ? 0 : (s & (jsc - 1))) * 4 + (rem & 3)) * 128;

    const int bz = blockIdx.z;
    A += (size_t)bz * sA;
    B += (size_t)bz * sB;

    const int tid  = threadIdx.x;
    const int lane = tid & 63;
    const int wave = tid >> 6;
    const int wy = wave >> 1, wx = wave & 1;
    const int quad = lane >> 4, l16 = lane & 15;

    // staging map: tile = 128 rows x 4 chunks of 16B; thread t handles
    // (row1 = t>>2, ch = t&3) and (row2 = row1+64, ch).
    const int row1 = tid >> 2, ch = tid & 3;
    const int row2 = row1 + 64;
    const int w1 = row1 * 32 + ((ch ^ (row1 & 3)) << 3);   // halves offset
    const int w2 = row2 * 32 + ((ch ^ (row2 & 3)) << 3);

    const f16* gA1 = A + (size_t)(i0 + row1) * lda + ch * 8;
    const f16* gA2 = A + (size_t)(i0 + row2) * lda + ch * 8;
    const f16* gB1 = B + (size_t)(j0 + row1) * ldb + ch * 8;
    const f16* gB2 = B + (size_t)(j0 + row2) * ldb + ch * 8;

    // frag-read slot: quad ^ (row&3); row&3 == l16&3 for all frag rows
    const int xa = (quad ^ (l16 & 3)) << 3;

    const int nt = K >> 5;
    float4 rA1[2], rA2[2], rB1[2], rB2[2];

    // prologue: tiles 0,1 -> reg sets 0,1
    rA1[0] = *(const float4*)(gA1);      rA2[0] = *(const float4*)(gA2);
    rB1[0] = *(const float4*)(gB1);      rB2[0] = *(const float4*)(gB2);
    rA1[1] = *(const float4*)(gA1 + 32); rA2[1] = *(const float4*)(gA2 + 32);
    rB1[1] = *(const float4*)(gB1 + 32); rB2[1] = *(const float4*)(gB2 + 32);

    floatx4 acc[4][4] = {};

    for (int t = 0; t < nt; ++t) {
        const int p = t & 1;
        // stage tile t (loaded 2 iters ago; waitcnt lands here, fully flown)
        *(float4*)&As[p][w1] = rA1[p];
        *(float4*)&As[p][w2] = rA2[p];
        *(float4*)&Bs[p][w1] = rB1[p];
        *(float4*)&Bs[p][w2] = rB2[p];
        // prefetch tile t+2 into the now-free reg set
        if (t + 2 < nt) {
            const int off = (t + 2) * 32;
            rA1[p] = *(const float4*)(gA1 + off);
            rA2[p] = *(const float4*)(gA2 + off);
            rB1[p] = *(const float4*)(gB1 + off);
            rB2[p] = *(const float4*)(gB2 + off);
        }
        __syncthreads();

        half8 af[4], bf[4];
        #pragma unroll
        for (int mi = 0; mi < 4; ++mi)
            af[mi] = *(const half8*)&As[p][(wy * 64 + mi * 16 + l16) * 32 + xa];
        #pragma unroll
        for (int ni = 0; ni < 4; ++ni)
            bf[ni] = *(const half8*)&Bs[p][(wx * 64 + ni * 16 + l16) * 32 + xa];
        #pragma unroll
        for (int mi = 0; mi < 4; ++mi)
            #pragma unroll
            for (int ni = 0; ni < 4; ++ni)
                acc[mi][ni] = __builtin_amdgcn_mfma_f32_16x16x32_f16(
                    af[mi], bf[ni], acc[mi][ni], 0, 0, 0);
    }

    // epilogue: C/D layout col = lane&15, row = quad*4 + reg (m89-verified)
    #pragma unroll
    for (int mi = 0; mi < 4; ++mi) {
        #pragma unroll
        for (int ni = 0; ni < 4; ++ni) {
            const int col = j0 + wx * 64 + ni * 16 + l16;
            #pragma unroll
            for (int r = 0; r < 4; ++r) {
                const int row = i0 + wy * 64 + mi * 16 + quad * 4 + r;
                float v = acc[mi][ni][r];
                if (MODE == 1) { v += bias[col]; v = v > 0.f ? v : 0.f; }
                if (MODE == 2) { v += bias[row]; v = v > 0.f ? v : 0.f; }
                if (MODE == 3) {
                    v += bias[row];
                    v = v > 0.f ? v : 0.f;
                    v += resid[(size_t)bz * sR + (size_t)row * ldc + col];
                    ((float*)Cp)[(size_t)bz * sC + (size_t)row * ldc + col] = v;
                } else {
                    ((f16*)Cp)[(size_t)bz * sC + (size_t)row * ldc + col] = (f16)v;
                }
            }
        }
    }
}

// ---------------------------------------------------------------------------
// in-place fp16 softmax over rows of 2048 (fp32 math)
// ---------------------------------------------------------------------------
__global__ __launch_bounds__(256) void softmax_f16_kernel(f16* __restrict__ S)
{
    f16* p = S + (size_t)blockIdx.x * T_DIM;
    const int tid = threadIdx.x;

    half8 hv = *((const half8*)p + tid);
    float v[8];
    float lmax = -1e30f;
    #pragma unroll
    for (int c = 0; c < 8; ++c) { v[c] = (float)hv[c]; lmax = fmaxf(lmax, v[c]); }
    #pragma unroll
    for (int off = 32; off; off >>= 1)
        lmax = fmaxf(lmax, __shfl_down(lmax, off));
    __shared__ float redm[4];
    if ((tid & 63) == 0) redm[tid >> 6] = lmax;
    __syncthreads();
    const float m = fmaxf(fmaxf(redm[0], redm[1]), fmaxf(redm[2], redm[3]));

    float lsum = 0.f;
    #pragma unroll
    for (int c = 0; c < 8; ++c) { v[c] = __expf(v[c] - m); lsum += v[c]; }
    #pragma unroll
    for (int off = 32; off; off >>= 1)
        lsum += __shfl_down(lsum, off);
    __shared__ float reds[4];
    if ((tid & 63) == 0) reds[tid >> 6] = lsum;
    __syncthreads();
    const float inv = 1.f / (reds[0] + reds[1] + reds[2] + reds[3]);

    #pragma unroll
    for (int c = 0; c < 8; ++c) hv[c] = (f16)(v[c] * inv);
    *((half8*)p + tid) = hv;
}

// ---------------------------------------------------------------------------
extern "C" void kernel_launch(void* const* d_in, const int* in_sizes, int n_in,
                              void* d_out, int out_size, void* d_ws, size_t ws_size,
                              hipStream_t stream)
{
    const float* x       = (const float*)d_in[0];
    const float* w_theta = (const float*)d_in[1];
    const float* b_theta = (const float*)d_in[2];
    const float* w_phi   = (const float*)d_in[3];
    const float* b_phi   = (const float*)d_in[4];
    const float* w_g     = (const float*)d_in[5];
    const float* b_g     = (const float*)d_in[6];
    const float* w_w     = (const float*)d_in[7];
    const float* b_w     = (const float*)d_in[8];
    float* out = (float*)d_out;

    const size_t FE = (size_t)B_DIM * C_DIM * T_DIM;   // 8.4M
    const size_t TC = (size_t)T_DIM * C_DIM;
    const size_t TT = (size_t)T_DIM * T_DIM;

    f16* xt      = (f16*)d_ws;
    f16* wtp     = xt + FE;              // merged theta|phi weights [1024][512]
    f16* wg_h    = wtp + 524288;
    f16* ww_h    = wg_h + 262144;
    float* btp   = (float*)(ww_h + 262144);   // merged bias [1024] fp32
    f16* tp      = (f16*)(btp + 1024);   // theta|phi acts [B][T][1024]
    f16* g       = tp + (size_t)B_DIM * T_DIM * 1024;
    f16* scores  = g + FE;               // B*T*T fp16 = 67 MB
    f16* feature = tp;                   // tp dead after scores GEMM

    const dim3 blk(256);

    convert_w_kernel<<<dim3(256, 1, 4), blk, 0, stream>>>(
        w_theta, w_phi, w_g, w_w, wtp, wtp + 262144, wg_h, ww_h);
    concat_bias_kernel<<<dim3(4), blk, 0, stream>>>(b_theta, b_phi, btp);
    transpose_x_kernel<<<dim3(T_DIM / 32, C_DIM / 32, B_DIM), blk, 0, stream>>>(x, xt);

    // merged theta|phi conv: tp[t][0:1024] = relu(xt . wtp + btp)  M=T,N=1024
    gemm_tn<1><<<dim3(1024 / 128, T_DIM / 128, B_DIM), blk, 0, stream>>>(
        xt, TC, C_DIM, wtp, 0, C_DIM, tp, (size_t)T_DIM * 1024, 1024,
        btp, nullptr, 0, C_DIM);
    // g[c][t] = relu(w_g . xt + b_g[c])   M=C, N=T
    gemm_tn<2><<<dim3(T_DIM / 128, C_DIM / 128, B_DIM), blk, 0, stream>>>(
        wg_h, 0, C_DIM, xt, TC, C_DIM, g, TC, T_DIM, b_g, nullptr, 0, C_DIM);
    // scores[i][j] = theta . phi   (theta = tp cols 0:512, phi = cols 512:1024)
    gemm_tn<0><<<dim3(T_DIM / 128, T_DIM / 128, B_DIM), blk, 0, stream>>>(
        tp, (size_t)T_DIM * 1024, 1024, tp + 512, (size_t)T_DIM * 1024, 1024,
        scores, TT, T_DIM, nullptr, nullptr, 0, C_DIM);
    softmax_f16_kernel<<<dim3(B_DIM * T_DIM), blk, 0, stream>>>(scores);
    // feature[i][c] = attn . g   M=T, N=C, K=T
    gemm_tn<0><<<dim3(C_DIM / 128, T_DIM / 128, B_DIM), blk, 0, stream>>>(
        scores, TT, T_DIM, g, TC, T_DIM, feature, TC, C_DIM, nullptr, nullptr, 0, T_DIM);
    // out[c][t] = relu(w_w . feature + b_w[c]) + x   M=C, N=T
    gemm_tn<3><<<dim3(T_DIM / 128, C_DIM / 128, B_DIM), blk, 0, stream>>>(
        ww_h, 0, C_DIM, feature, TC, C_DIM, out, TC, T_DIM, b_w, x, TC, C_DIM);
}

// Round 6
// 274.087 us; speedup vs baseline: 2.2667x; 2.2667x over previous
//
#include <hip/hip_runtime.h>
#include <math.h>

#define C_DIM 512
#define T_DIM 2048
#define B_DIM 8

typedef _Float16 f16;
typedef __attribute__((ext_vector_type(8))) _Float16 half8;
typedef __attribute__((ext_vector_type(4))) _Float16 half4;
typedef __attribute__((ext_vector_type(4))) float floatx4;

// ---------------------------------------------------------------------------
// fp32 [512][512] weights -> fp16. z=0/1 fill merged theta|phi [1024][512].
// ---------------------------------------------------------------------------
__global__ __launch_bounds__(256) void convert_w_kernel(
    const float* __restrict__ w0, const float* __restrict__ w1,
    const float* __restrict__ w2, const float* __restrict__ w3,
    f16* __restrict__ o0, f16* __restrict__ o1,
    f16* __restrict__ o2, f16* __restrict__ o3)
{
    const float* src; f16* dst;
    switch (blockIdx.z) {
        case 0:  src = w0; dst = o0; break;
        case 1:  src = w1; dst = o1; break;
        case 2:  src = w2; dst = o2; break;
        default: src = w3; dst = o3; break;
    }
    const int idx = (blockIdx.x * 256 + threadIdx.x) * 4;
    const float4 v = *(const float4*)(src + idx);
    half4 h; h[0] = (f16)v.x; h[1] = (f16)v.y; h[2] = (f16)v.z; h[3] = (f16)v.w;
    *(half4*)(dst + idx) = h;
}

__global__ __launch_bounds__(256) void concat_bias_kernel(
    const float* __restrict__ b0, const float* __restrict__ b1,
    float* __restrict__ o)
{
    const int i = blockIdx.x * 256 + threadIdx.x;   // 1024 threads
    o[i] = (i < 512) ? b0[i] : b1[i - 512];
}

// ---------------------------------------------------------------------------
// x [B][C][T] fp32 -> xt [B][T][C] fp16 (32x32 LDS tile transpose)
// ---------------------------------------------------------------------------
__global__ __launch_bounds__(256) void transpose_x_kernel(
    const float* __restrict__ x, f16* __restrict__ xt)
{
    __shared__ float xs[32][33];
    const int b  = blockIdx.z;
    const int t0 = blockIdx.x * 32, c0 = blockIdx.y * 32;
    const float* xb = x + (size_t)b * C_DIM * T_DIM;
    const int r = threadIdx.x >> 3, q = threadIdx.x & 7;

    const float4 v = *(const float4*)(xb + (size_t)(c0 + r) * T_DIM + t0 + q * 4);
    xs[r][q * 4 + 0] = v.x; xs[r][q * 4 + 1] = v.y;
    xs[r][q * 4 + 2] = v.z; xs[r][q * 4 + 3] = v.w;
    __syncthreads();

    f16* xtb = xt + (size_t)b * C_DIM * T_DIM;
    half4 h;
    h[0] = (f16)xs[q * 4 + 0][r]; h[1] = (f16)xs[q * 4 + 1][r];
    h[2] = (f16)xs[q * 4 + 2][r]; h[3] = (f16)xs[q * 4 + 3][r];
    *(half4*)(xtb + (size_t)(t0 + r) * C_DIM + c0 + q * 4) = h;
}

// ---------------------------------------------------------------------------
// TN MFMA GEMM: C[i][j] = sum_k A[i][k] * B[j][k]
// 128x128 tile, BK=32. Register-staged prefetch at DISTANCE 2, loop unrolled
// 2x with NAMED register sets (R5's rA[p] with runtime p forced scratch
// spills -> 444 MB/dispatch of HBM spill traffic; named vars keep it in
// VGPRs). Even iter: set0/LDS buf0; odd: set1/buf1; prefetch t+2 into the
// just-staged set. Plain VGPR global_loads are not drained at s_barrier, so
// each load gets ~2 iterations of flight.
// XOR slot swizzle (slot = ch ^ (row&3)) on write and frag-read.
// MODE: 0 = f16 store; 1 = f16 relu(+bias[col]); 2 = f16 relu(+bias[row]);
// 3 = fp32 relu(+bias[row]) + resid.
// ---------------------------------------------------------------------------
template<int MODE>
__global__ __launch_bounds__(256) void gemm_tn(
    const f16* __restrict__ A, size_t sA, int lda,
    const f16* __restrict__ B, size_t sB, int ldb,
    void* __restrict__ Cp, size_t sC, int ldc,
    const float* __restrict__ bias,
    const float* __restrict__ resid, size_t sR,
    int K)
{
    __shared__ __align__(16) f16 As[2][128 * 32];   // 2 x 8 KB, unpadded
    __shared__ __align__(16) f16 Bs[2][128 * 32];

    // 4x4-supertile block swizzle: 16 consecutive blocks share 4 A + 4 B tiles
    const int gx = gridDim.x;
    const int flat = blockIdx.y * gx + blockIdx.x;
    const int jsc = gx >> 2;                  // j-supertiles per row
    const int sh = (jsc <= 1) ? 0 : (31 - __builtin_clz(jsc));
    const int s = flat >> 4, rem = flat & 15;
    const int i0 = ((s >> sh) * 4 + (rem >> 2)) * 128;
    const int j0 = (((jsc <= 1) ? 0 : (s & (jsc - 1))) * 4 + (rem & 3)) * 128;

    const int bz = blockIdx.z;
    A += (size_t)bz * sA;
    B += (size_t)bz * sB;

    const int tid  = threadIdx.x;
    const int lane = tid & 63;
    const int wave = tid >> 6;
    const int wy = wave >> 1, wx = wave & 1;
    const int quad = lane >> 4, l16 = lane & 15;

    // staging map: tile = 128 rows x 4 chunks of 16B; thread t handles
    // (row1 = t>>2, ch = t&3) and (row2 = row1+64, ch).
    const int row1 = tid >> 2, ch = tid & 3;
    const int row2 = row1 + 64;
    const int w1 = row1 * 32 + ((ch ^ (row1 & 3)) << 3);   // halves offset
    const int w2 = row2 * 32 + ((ch ^ (row2 & 3)) << 3);

    const f16* gA1 = A + (size_t)(i0 + row1) * lda + ch * 8;
    const f16* gA2 = A + (size_t)(i0 + row2) * lda + ch * 8;
    const f16* gB1 = B + (size_t)(j0 + row1) * ldb + ch * 8;
    const f16* gB2 = B + (size_t)(j0 + row2) * ldb + ch * 8;

    // frag-read slot: quad ^ (row&3); row&3 == l16&3 for all frag rows
    const int xa = (quad ^ (l16 & 3)) << 3;

    const int nt = K >> 5;   // always even here (16 or 64)

    // prologue: tile 0 -> set0, tile 1 -> set1
    float4 a1_0 = *(const float4*)(gA1);      float4 a2_0 = *(const float4*)(gA2);
    float4 b1_0 = *(const float4*)(gB1);      float4 b2_0 = *(const float4*)(gB2);
    float4 a1_1 = *(const float4*)(gA1 + 32); float4 a2_1 = *(const float4*)(gA2 + 32);
    float4 b1_1 = *(const float4*)(gB1 + 32); float4 b2_1 = *(const float4*)(gB2 + 32);

    floatx4 acc[4][4] = {};

    for (int t = 0; t < nt; t += 2) {
        // ---- even iter: buffer 0, set 0 ----
        *(float4*)&As[0][w1] = a1_0;
        *(float4*)&As[0][w2] = a2_0;
        *(float4*)&Bs[0][w1] = b1_0;
        *(float4*)&Bs[0][w2] = b2_0;
        if (t + 2 < nt) {
            const int off = (t + 2) * 32;
            a1_0 = *(const float4*)(gA1 + off); a2_0 = *(const float4*)(gA2 + off);
            b1_0 = *(const float4*)(gB1 + off); b2_0 = *(const float4*)(gB2 + off);
        }
        __syncthreads();
        {
            half8 af[4], bf[4];
            #pragma unroll
            for (int mi = 0; mi < 4; ++mi)
                af[mi] = *(const half8*)&As[0][(wy * 64 + mi * 16 + l16) * 32 + xa];
            #pragma unroll
            for (int ni = 0; ni < 4; ++ni)
                bf[ni] = *(const half8*)&Bs[0][(wx * 64 + ni * 16 + l16) * 32 + xa];
            #pragma unroll
            for (int mi = 0; mi < 4; ++mi)
                #pragma unroll
                for (int ni = 0; ni < 4; ++ni)
                    acc[mi][ni] = __builtin_amdgcn_mfma_f32_16x16x32_f16(
                        af[mi], bf[ni], acc[mi][ni], 0, 0, 0);
        }
        // ---- odd iter: buffer 1, set 1 ----
        *(float4*)&As[1][w1] = a1_1;
        *(float4*)&As[1][w2] = a2_1;
        *(float4*)&Bs[1][w1] = b1_1;
        *(float4*)&Bs[1][w2] = b2_1;
        if (t + 3 < nt) {
            const int off = (t + 3) * 32;
            a1_1 = *(const float4*)(gA1 + off); a2_1 = *(const float4*)(gA2 + off);
            b1_1 = *(const float4*)(gB1 + off); b2_1 = *(const float4*)(gB2 + off);
        }
        __syncthreads();
        {
            half8 af[4], bf[4];
            #pragma unroll
            for (int mi = 0; mi < 4; ++mi)
                af[mi] = *(const half8*)&As[1][(wy * 64 + mi * 16 + l16) * 32 + xa];
            #pragma unroll
            for (int ni = 0; ni < 4; ++ni)
                bf[ni] = *(const half8*)&Bs[1][(wx * 64 + ni * 16 + l16) * 32 + xa];
            #pragma unroll
            for (int mi = 0; mi < 4; ++mi)
                #pragma unroll
                for (int ni = 0; ni < 4; ++ni)
                    acc[mi][ni] = __builtin_amdgcn_mfma_f32_16x16x32_f16(
                        af[mi], bf[ni], acc[mi][ni], 0, 0, 0);
        }
    }

    // epilogue: C/D layout col = lane&15, row = quad*4 + reg (m89-verified)
    #pragma unroll
    for (int mi = 0; mi < 4; ++mi) {
        #pragma unroll
        for (int ni = 0; ni < 4; ++ni) {
            const int col = j0 + wx * 64 + ni * 16 + l16;
            #pragma unroll
            for (int r = 0; r < 4; ++r) {
                const int row = i0 + wy * 64 + mi * 16 + quad * 4 + r;
                float v = acc[mi][ni][r];
                if (MODE == 1) { v += bias[col]; v = v > 0.f ? v : 0.f; }
                if (MODE == 2) { v += bias[row]; v = v > 0.f ? v : 0.f; }
                if (MODE == 3) {
                    v += bias[row];
                    v = v > 0.f ? v : 0.f;
                    v += resid[(size_t)bz * sR + (size_t)row * ldc + col];
                    ((float*)Cp)[(size_t)bz * sC + (size_t)row * ldc + col] = v;
                } else {
                    ((f16*)Cp)[(size_t)bz * sC + (size_t)row * ldc + col] = (f16)v;
                }
            }
        }
    }
}

// ---------------------------------------------------------------------------
// in-place fp16 softmax over rows of 2048 (fp32 math)
// ---------------------------------------------------------------------------
__global__ __launch_bounds__(256) void softmax_f16_kernel(f16* __restrict__ S)
{
    f16* p = S + (size_t)blockIdx.x * T_DIM;
    const int tid = threadIdx.x;

    half8 hv = *((const half8*)p + tid);
    float v[8];
    float lmax = -1e30f;
    #pragma unroll
    for (int c = 0; c < 8; ++c) { v[c] = (float)hv[c]; lmax = fmaxf(lmax, v[c]); }
    #pragma unroll
    for (int off = 32; off; off >>= 1)
        lmax = fmaxf(lmax, __shfl_down(lmax, off));
    __shared__ float redm[4];
    if ((tid & 63) == 0) redm[tid >> 6] = lmax;
    __syncthreads();
    const float m = fmaxf(fmaxf(redm[0], redm[1]), fmaxf(redm[2], redm[3]));

    float lsum = 0.f;
    #pragma unroll
    for (int c = 0; c < 8; ++c) { v[c] = __expf(v[c] - m); lsum += v[c]; }
    #pragma unroll
    for (int off = 32; off; off >>= 1)
        lsum += __shfl_down(lsum, off);
    __shared__ float reds[4];
    if ((tid & 63) == 0) reds[tid >> 6] = lsum;
    __syncthreads();
    const float inv = 1.f / (reds[0] + reds[1] + reds[2] + reds[3]);

    #pragma unroll
    for (int c = 0; c < 8; ++c) hv[c] = (f16)(v[c] * inv);
    *((half8*)p + tid) = hv;
}

// ---------------------------------------------------------------------------
extern "C" void kernel_launch(void* const* d_in, const int* in_sizes, int n_in,
                              void* d_out, int out_size, void* d_ws, size_t ws_size,
                              hipStream_t stream)
{
    const float* x       = (const float*)d_in[0];
    const float* w_theta = (const float*)d_in[1];
    const float* b_theta = (const float*)d_in[2];
    const float* w_phi   = (const float*)d_in[3];
    const float* b_phi   = (const float*)d_in[4];
    const float* w_g     = (const float*)d_in[5];
    const float* b_g     = (const float*)d_in[6];
    const float* w_w     = (const float*)d_in[7];
    const float* b_w     = (const float*)d_in[8];
    float* out = (float*)d_out;

    const size_t FE = (size_t)B_DIM * C_DIM * T_DIM;   // 8.4M
    const size_t TC = (size_t)T_DIM * C_DIM;
    const size_t TT = (size_t)T_DIM * T_DIM;

    f16* xt      = (f16*)d_ws;
    f16* wtp     = xt + FE;              // merged theta|phi weights [1024][512]
    f16* wg_h    = wtp + 524288;
    f16* ww_h    = wg_h + 262144;
    float* btp   = (float*)(ww_h + 262144);   // merged bias [1024] fp32
    f16* tp      = (f16*)(btp + 1024);   // theta|phi acts [B][T][1024]
    f16* g       = tp + (size_t)B_DIM * T_DIM * 1024;
    f16* scores  = g + FE;               // B*T*T fp16 = 67 MB
    f16* feature = tp;                   // tp dead after scores GEMM

    const dim3 blk(256);

    convert_w_kernel<<<dim3(256, 1, 4), blk, 0, stream>>>(
        w_theta, w_phi, w_g, w_w, wtp, wtp + 262144, wg_h, ww_h);
    concat_bias_kernel<<<dim3(4), blk, 0, stream>>>(b_theta, b_phi, btp);
    transpose_x_kernel<<<dim3(T_DIM / 32, C_DIM / 32, B_DIM), blk, 0, stream>>>(x, xt);

    // merged theta|phi conv: tp[t][0:1024] = relu(xt . wtp + btp)  M=T,N=1024
    gemm_tn<1><<<dim3(1024 / 128, T_DIM / 128, B_DIM), blk, 0, stream>>>(
        xt, TC, C_DIM, wtp, 0, C_DIM, tp, (size_t)T_DIM * 1024, 1024,
        btp, nullptr, 0, C_DIM);
    // g[c][t] = relu(w_g . xt + b_g[c])   M=C, N=T
    gemm_tn<2><<<dim3(T_DIM / 128, C_DIM / 128, B_DIM), blk, 0, stream>>>(
        wg_h, 0, C_DIM, xt, TC, C_DIM, g, TC, T_DIM, b_g, nullptr, 0, C_DIM);
    // scores[i][j] = theta . phi   (theta = tp cols 0:512, phi = cols 512:1024)
    gemm_tn<0><<<dim3(T_DIM / 128, T_DIM / 128, B_DIM), blk, 0, stream>>>(
        tp, (size_t)T_DIM * 1024, 1024, tp + 512, (size_t)T_DIM * 1024, 1024,
        scores, TT, T_DIM, nullptr, nullptr, 0, C_DIM);
    softmax_f16_kernel<<<dim3(B_DIM * T_DIM), blk, 0, stream>>>(scores);
    // feature[i][c] = attn . g   M=T, N=C, K=T
    gemm_tn<0><<<dim3(C_DIM / 128, T_DIM / 128, B_DIM), blk, 0, stream>>>(
        scores, TT, T_DIM, g, TC, T_DIM, feature, TC, C_DIM, nullptr, nullptr, 0, T_DIM);
    // out[c][t] = relu(w_w . feature + b_w[c]) + x   M=C, N=T
    gemm_tn<3><<<dim3(T_DIM / 128, C_DIM / 128, B_DIM), blk, 0, stream>>>(
        ww_h, 0, C_DIM, feature, TC, C_DIM, out, TC, T_DIM, b_w, x, TC, C_DIM);
}